// Round 4
// baseline (1784.732 us; speedup 1.0000x reference)
//
#include <hip/hip_runtime.h>
#include <hip/hip_bf16.h>
#include <math.h>

using bf16 = __hip_bfloat16;
typedef __bf16 bf16x8 __attribute__((ext_vector_type(8)));
typedef float floatx4 __attribute__((ext_vector_type(4)));

__device__ __forceinline__ float bf2f(bf16 x) { return __bfloat162float(x); }
__device__ __forceinline__ bf16 f2bf(float x) { return __float2bfloat16(x); }

// flag semantics: flagp[0] == 1 -> external tensors are bf16; 0 -> float32.
__device__ __forceinline__ float loadExt(const void* p, long i, int f32) {
  return f32 ? ((const float*)p)[i] : bf2f(((const bf16*)p)[i]);
}
__device__ __forceinline__ void storeExt(void* p, long i, int f32, float v) {
  if (f32) ((float*)p)[i] = v;
  else     ((bf16*)p)[i] = f2bf(v);
}

// ---------------- dtype detector: 1 wave, inspects low 16 bits of 64 words ---
__global__ void detect_kernel(const unsigned int* __restrict__ q, int* __restrict__ flag) {
  const int lane = threadIdx.x;
  const unsigned int w = q[lane];
  const unsigned int lo = w & 0xffffu;
  const unsigned int e = (lo >> 7) & 0xffu;
  const bool ok = (lo == 0u) || (e >= 100u && e <= 141u);  // plausible bf16 from N(0,1)
  const unsigned long long m = __ballot(ok);
  if (lane == 0) flag[0] = (__popcll(m) == 64) ? 1 : 0;
}

// ---------------- convert external array -> canonical bf16 ----------------
__global__ void cvt_kernel(const int* __restrict__ flagp, const void* __restrict__ src,
                           bf16* __restrict__ dst, int n) {
  const int f32 = (flagp[0] == 0);
  for (int i = blockIdx.x * blockDim.x + threadIdx.x; i < n; i += gridDim.x * blockDim.x)
    dst[i] = f2bf(loadExt(src, i, f32));
}

// ---------------- naive weight transpose (canonical bf16): in[K,N]->out[N,K] -
__global__ void transpose_kernel(const bf16* __restrict__ in, bf16* __restrict__ out,
                                 int K, int N) {
  int i = blockIdx.x * blockDim.x + threadIdx.x;
  if (i >= K * N) return;
  int k = i / N, n = i - k * N;
  out[n * K + k] = in[i];
}

// ---------------- LayerNorm: one wave per 192-elem row; external input ------
__global__ __launch_bounds__(256) void ln_kernel(const int* __restrict__ flagp,
                                                 const void* __restrict__ x, long row0,
                                                 const bf16* __restrict__ g,
                                                 const bf16* __restrict__ b,
                                                 bf16* __restrict__ out) {
  const int f32 = (flagp[0] == 0);
  const int row = blockIdx.x * 4 + (threadIdx.x >> 6);
  const int lane = threadIdx.x & 63;
  const long gbase = (row0 + row) * 192;
  float v0 = loadExt(x, gbase + lane, f32);
  float v1 = loadExt(x, gbase + lane + 64, f32);
  float v2 = loadExt(x, gbase + lane + 128, f32);
  float s = v0 + v1 + v2;
  #pragma unroll
  for (int off = 32; off > 0; off >>= 1) s += __shfl_xor(s, off, 64);
  const float mu = s * (1.0f / 192.0f);
  float d0 = v0 - mu, d1 = v1 - mu, d2 = v2 - mu;
  float vv = d0 * d0 + d1 * d1 + d2 * d2;
  #pragma unroll
  for (int off = 32; off > 0; off >>= 1) vv += __shfl_xor(vv, off, 64);
  const float rstd = rsqrtf(vv * (1.0f / 192.0f) + 1e-5f);
  bf16* orow = out + (long)row * 192;
  orow[lane]       = f2bf(d0 * rstd * bf2f(g[lane])       + bf2f(b[lane]));
  orow[lane + 64]  = f2bf(d1 * rstd * bf2f(g[lane + 64])  + bf2f(b[lane + 64]));
  orow[lane + 128] = f2bf(d2 * rstd * bf2f(g[lane + 128]) + bf2f(b[lane + 128]));
}

// ---------------- bf16 MFMA GEMM: C = A[M,K]*BT[N,K]^T + bias, epilogue -----
// EPI: 0 = bias, 1 = bias+GELU(exact), 2 = bias+residual.
// res/out may be external-dtype (res_ext/out_ext=1) with row offset ext_row0.
template <int EPI>
__global__ __launch_bounds__(256) void gemm_bt(const bf16* __restrict__ A,
                                               const bf16* __restrict__ BT,
                                               const bf16* __restrict__ bias,
                                               const int* __restrict__ flagp,
                                               const void* res, int res_ext,
                                               void* out, int out_ext, long ext_row0,
                                               int M, int N, int K) {
  constexpr int LDA = 40;  // 32 + 8 pad
  __shared__ __align__(16) bf16 As[128 * LDA];
  __shared__ __align__(16) bf16 Bs[64 * LDA];
  const int xf32 = (flagp[0] == 0);
  const int tid = threadIdx.x;
  const int wave = tid >> 6;
  const int lane = tid & 63;
  const int l16 = lane & 15;
  const int quad = lane >> 4;
  const long m0 = (long)blockIdx.x * 128;
  const int n0 = blockIdx.y * 64;

  floatx4 acc[2][4];
  #pragma unroll
  for (int i = 0; i < 2; i++)
    #pragma unroll
    for (int j = 0; j < 4; j++) acc[i][j] = (floatx4){0.f, 0.f, 0.f, 0.f};

  const int arow0 = tid >> 2;            // 0..63
  const int arow1 = arow0 + 64;          // 64..127
  const int acol = (tid & 3) * 8;        // 0/8/16/24

  for (int k0 = 0; k0 < K; k0 += 32) {
    *(float4*)&As[arow0 * LDA + acol] = *(const float4*)&A[(m0 + arow0) * K + k0 + acol];
    *(float4*)&As[arow1 * LDA + acol] = *(const float4*)&A[(m0 + arow1) * K + k0 + acol];
    *(float4*)&Bs[arow0 * LDA + acol] = *(const float4*)&BT[(long)(n0 + arow0) * K + k0 + acol];
    __syncthreads();

    bf16x8 af[2], bfr[4];
    #pragma unroll
    for (int ms = 0; ms < 2; ms++)
      af[ms] = *(const bf16x8*)&As[(wave * 32 + ms * 16 + l16) * LDA + quad * 8];
    #pragma unroll
    for (int ns = 0; ns < 4; ns++)
      bfr[ns] = *(const bf16x8*)&Bs[(ns * 16 + l16) * LDA + quad * 8];

    #pragma unroll
    for (int ms = 0; ms < 2; ms++)
      #pragma unroll
      for (int ns = 0; ns < 4; ns++)
        acc[ms][ns] = __builtin_amdgcn_mfma_f32_16x16x32_bf16(af[ms], bfr[ns], acc[ms][ns], 0, 0, 0);
    __syncthreads();
  }

  // epilogue: C/D layout col = lane&15, row = quad*4 + r
  #pragma unroll
  for (int ms = 0; ms < 2; ms++) {
    #pragma unroll
    for (int ns = 0; ns < 4; ns++) {
      #pragma unroll
      for (int r = 0; r < 4; r++) {
        const long row = m0 + wave * 32 + ms * 16 + quad * 4 + r;
        const int col = n0 + ns * 16 + l16;
        float v = acc[ms][ns][r] + bf2f(bias[col]);
        if (EPI == 1) v = 0.5f * v * (1.0f + erff(v * 0.70710678118654752f));
        if (EPI == 2) v += loadExt(res, (ext_row0 + row) * N + col, res_ext && xf32);
        const long oi = out_ext ? (ext_row0 + row) * N + col : row * (long)N + col;
        storeExt(out, oi, out_ext && xf32, v);
      }
    }
  }
}

// ---------------- scalar window attention (batch-local), canonical bf16 -----
__global__ __launch_bounds__(64) void attn_kernel(const bf16* __restrict__ qkv,  // [12544,576]
                                                  const bf16* __restrict__ rpb,  // [169,6] canonical
                                                  bf16* __restrict__ out) {      // [12544,192]
  __shared__ float qs[49][32];
  __shared__ float ks[49][32];
  __shared__ float vs[49][32];
  __shared__ float sc[49][52];
  __shared__ int rowIdx[49];
  __shared__ int regn[49];
  const int lane = threadIdx.x;
  const int unit = blockIdx.x;          // [0, 1536)
  const int head = unit % 6;
  const int wIdx = unit / 6;            // [0, 256)
  const int wh = wIdx >> 4;
  const int ww = wIdx & 15;

  if (lane < 49) {
    const int r = lane / 7, c = lane - 7 * (lane / 7);
    const int hr = wh * 7 + r;          // rolled-image coords
    const int wr = ww * 7 + c;
    int h = hr + 3; if (h >= 112) h -= 112;   // reverse the roll(-3) gather
    int w = wr + 3; if (w >= 112) w -= 112;
    rowIdx[lane] = h * 112 + w;               // batch-local row (original order)
    const int rh = hr < 105 ? 0 : (hr < 109 ? 1 : 2);
    const int rw = wr < 105 ? 0 : (wr < 109 ? 1 : 2);
    regn[lane] = rh * 3 + rw;
  }
  __syncthreads();

  const float scale = 0.17677669529663687f;  // 1/sqrt(32)
  for (int i = lane; i < 49 * 32; i += 64) {
    const int n = i >> 5, d = i & 31;
    const long base = (long)rowIdx[n] * 576 + head * 32 + d;
    qs[n][d] = bf2f(qkv[base]) * scale;
    ks[n][d] = bf2f(qkv[base + 192]);
    vs[n][d] = bf2f(qkv[base + 384]);
  }
  __syncthreads();

  for (int i = lane; i < 49 * 49; i += 64) {
    const int n = i / 49, m = i - n * 49;
    float s = 0.f;
    #pragma unroll
    for (int d = 0; d < 32; d++) s += qs[n][d] * ks[m][d];
    const int r1 = n / 7, c1 = n - 7 * r1, r2 = m / 7, c2 = m - 7 * r2;
    s += bf2f(rpb[((r1 - r2 + 6) * 13 + (c1 - c2 + 6)) * 6 + head]);
    if (regn[n] != regn[m]) s -= 100.0f;
    sc[n][m] = s;
  }
  __syncthreads();

  if (lane < 49) {
    float mx = -1e30f;
    for (int m = 0; m < 49; m++) mx = fmaxf(mx, sc[lane][m]);
    float sum = 0.f;
    for (int m = 0; m < 49; m++) { float e = __expf(sc[lane][m] - mx); sc[lane][m] = e; sum += e; }
    const float inv = 1.0f / sum;
    for (int m = 0; m < 49; m++) sc[lane][m] *= inv;
  }
  __syncthreads();

  for (int i = lane; i < 49 * 32; i += 64) {
    const int n = i >> 5, d = i & 31;
    float s = 0.f;
    for (int m = 0; m < 49; m++) s += sc[n][m] * vs[m][d];
    out[(long)rowIdx[n] * 192 + head * 32 + d] = f2bf(s);
  }
}

// ---------------------------------------------------------------------------
// ws layout: [int flag][pad to 16B] then bf16: wsA [12544,192], wsB [12544,576],
// canonical params (qkv_w,qkv_b,rpb,proj_w,proj_b,n1g,n1b,n2g,n2b,fc1_w,fc1_b,
// fc2_w,fc2_b), transposed weights. Total ~21.1 MB.
extern "C" void kernel_launch(void* const* d_in, const int* in_sizes, int n_in,
                              void* d_out, int out_size, void* d_ws, size_t ws_size,
                              hipStream_t stream) {
  const void* query   = d_in[0];
  const void* norm1_g = d_in[1];
  const void* norm1_b = d_in[2];
  const void* qkv_w   = d_in[3];
  const void* qkv_b   = d_in[4];
  const void* rpb     = d_in[5];
  const void* proj_w  = d_in[6];
  const void* proj_b  = d_in[7];
  const void* norm2_g = d_in[8];
  const void* norm2_b = d_in[9];
  const void* fc1_w   = d_in[10];
  const void* fc1_b   = d_in[11];
  const void* fc2_w   = d_in[12];
  const void* fc2_b   = d_in[13];

  const long MB_ = 12544;   // rows per batch image
  const long CH  = 6272;    // rows per MLP chunk (16 chunks)

  int* flag  = (int*)d_ws;
  bf16* base = (bf16*)((char*)d_ws + 16);
  bf16* wsA   = base;                   // 2,408,448
  bf16* wsB   = wsA + MB_ * 192;        // 7,225,344
  bf16* pQKVW = wsB + MB_ * 576;        // 110592
  bf16* pQKVB = pQKVW + 110592;         // 576
  bf16* pRPB  = pQKVB + 576;            // 1014
  bf16* pPRJW = pRPB + 1014;            // 36864
  bf16* pPRJB = pPRJW + 36864;          // 192
  bf16* pN1G  = pPRJB + 192;            // 192
  bf16* pN1B  = pN1G + 192;             // 192
  bf16* pN2G  = pN1B + 192;             // 192
  bf16* pN2B  = pN2G + 192;             // 192
  bf16* pFC1W = pN2B + 192;             // 147456
  bf16* pFC1B = pFC1W + 147456;         // 768
  bf16* pFC2W = pFC1B + 768;            // 147456
  bf16* pFC2B = pFC2W + 147456;         // 192
  bf16* qkvT  = pFC2B + 192;            // 110592
  bf16* projT = qkvT + 110592;          // 36864
  bf16* fc1T  = projT + 36864;          // 147456
  bf16* fc2T  = fc1T + 147456;          // 147456

  detect_kernel<<<1, 64, 0, stream>>>((const unsigned int*)query, flag);

  auto cvt = [&](const void* src, bf16* dst, int n) {
    cvt_kernel<<<(n + 255) / 256, 256, 0, stream>>>(flag, src, dst, n);
  };
  cvt(qkv_w, pQKVW, 110592);
  cvt(qkv_b, pQKVB, 576);
  cvt(rpb, pRPB, 1014);
  cvt(proj_w, pPRJW, 36864);
  cvt(proj_b, pPRJB, 192);
  cvt(norm1_g, pN1G, 192);
  cvt(norm1_b, pN1B, 192);
  cvt(norm2_g, pN2G, 192);
  cvt(norm2_b, pN2B, 192);
  cvt(fc1_w, pFC1W, 147456);
  cvt(fc1_b, pFC1B, 768);
  cvt(fc2_w, pFC2W, 147456);
  cvt(fc2_b, pFC2B, 192);

  transpose_kernel<<<(192 * 576 + 255) / 256, 256, 0, stream>>>(pQKVW, qkvT, 192, 576);
  transpose_kernel<<<(192 * 192 + 255) / 256, 256, 0, stream>>>(pPRJW, projT, 192, 192);
  transpose_kernel<<<(192 * 768 + 255) / 256, 256, 0, stream>>>(pFC1W, fc1T, 192, 768);
  transpose_kernel<<<(768 * 192 + 255) / 256, 256, 0, stream>>>(pFC2W, fc2T, 768, 192);

  // ---- attention phase, per batch image ----
  for (int b = 0; b < 8; b++) {
    const long r0 = b * MB_;
    // LN1: query rows [r0, r0+MB_) -> wsA
    ln_kernel<<<MB_ / 4, 256, 0, stream>>>(flag, query, r0, pN1G, pN1B, wsA);
    // qkv = ln1 @ qkv_w + b : wsA -> wsB (internal)
    gemm_bt<0><<<dim3(98, 9), 256, 0, stream>>>(wsA, qkvT, pQKVB, flag,
                                                nullptr, 0, wsB, 0, 0, (int)MB_, 576, 192);
    // attention: wsB -> wsA
    attn_kernel<<<1536, 64, 0, stream>>>(wsB, pRPB, wsA);
    // x = query + attn @ proj_w + b : -> d_out rows [r0, r0+MB_) (external)
    gemm_bt<2><<<dim3(98, 3), 256, 0, stream>>>(wsA, projT, pPRJB, flag,
                                                query, 1, d_out, 1, r0, (int)MB_, 192, 192);
  }

  // ---- MLP phase, per 6272-row chunk ----
  for (int c = 0; c < 16; c++) {
    const long r0 = c * CH;
    // LN2: d_out rows (external) -> wsA
    ln_kernel<<<CH / 4, 256, 0, stream>>>(flag, d_out, r0, pN2G, pN2B, wsA);
    // h = gelu(ln2 @ fc1 + b) : wsA -> wsB (internal)
    gemm_bt<1><<<dim3(49, 12), 256, 0, stream>>>(wsA, fc1T, pFC1B, flag,
                                                 nullptr, 0, wsB, 0, 0, (int)CH, 768, 192);
    // out = x + h @ fc2 + b : in place on d_out rows (external)
    gemm_bt<2><<<dim3(49, 3), 256, 0, stream>>>(wsB, fc2T, pFC2B, flag,
                                                d_out, 1, d_out, 1, r0, (int)CH, 192, 768);
  }
}

// Round 5
// 1150.822 us; speedup vs baseline: 1.5508x; 1.5508x over previous
//
#include <hip/hip_runtime.h>
#include <hip/hip_bf16.h>
#include <math.h>

using bf16 = __hip_bfloat16;
typedef __bf16 bf16x8 __attribute__((ext_vector_type(8)));
typedef float floatx4 __attribute__((ext_vector_type(4)));

__device__ __forceinline__ float bf2f(bf16 x) { return __bfloat162float(x); }
__device__ __forceinline__ bf16 f2bf(float x) { return __float2bfloat16(x); }

// flag semantics: flagp[0] == 1 -> external tensors are bf16; 0 -> float32.
__device__ __forceinline__ float loadExt(const void* p, long i, int f32) {
  return f32 ? ((const float*)p)[i] : bf2f(((const bf16*)p)[i]);
}
__device__ __forceinline__ void storeExt(void* p, long i, int f32, float v) {
  if (f32) ((float*)p)[i] = v;
  else     ((bf16*)p)[i] = f2bf(v);
}

// ---------------- dtype detector: 1 wave, inspects low 16 bits of 64 words ---
__global__ void detect_kernel(const unsigned int* __restrict__ q, int* __restrict__ flag) {
  const int lane = threadIdx.x;
  const unsigned int w = q[lane];
  const unsigned int lo = w & 0xffffu;
  const unsigned int e = (lo >> 7) & 0xffu;
  const bool ok = (lo == 0u) || (e >= 100u && e <= 141u);  // plausible bf16 from N(0,1)
  const unsigned long long m = __ballot(ok);
  if (lane == 0) flag[0] = (__popcll(m) == 64) ? 1 : 0;
}

// ---------------- combined 1-D param convert: 9 tensors -> contiguous bf16 ---
// layout in dst: qkv_b[576] proj_b[192] n1g[192] n1b[192] n2g[192] n2b[192]
//               fc1_b[768] fc2_b[192] rpb[1014]   total 3510
__global__ void cvt_params_kernel(const int* __restrict__ flagp,
                                  const void* qkv_b, const void* proj_b,
                                  const void* n1g, const void* n1b,
                                  const void* n2g, const void* n2b,
                                  const void* fc1_b, const void* fc2_b,
                                  const void* rpb, bf16* __restrict__ dst) {
  const int f32 = (flagp[0] == 0);
  int i = blockIdx.x * blockDim.x + threadIdx.x;
  if (i >= 3510) return;
  const void* src; int j = i;
  if      (j < 576)  { src = qkv_b; }
  else if ((j -= 576)  < 192) { src = proj_b; }
  else if ((j -= 192)  < 192) { src = n1g; }
  else if ((j -= 192)  < 192) { src = n1b; }
  else if ((j -= 192)  < 192) { src = n2g; }
  else if ((j -= 192)  < 192) { src = n2b; }
  else if ((j -= 192)  < 768) { src = fc1_b; }
  else if ((j -= 768)  < 192) { src = fc2_b; }
  else { j -= 192; src = rpb; }
  dst[i] = f2bf(loadExt(src, j, f32));
}

// ---------------- fused convert + transpose: src[K,N] (ext) -> dst[N,K] bf16 -
__global__ void cvtT_kernel(const int* __restrict__ flagp, const void* __restrict__ src,
                            bf16* __restrict__ dst, int K, int N) {
  const int f32 = (flagp[0] == 0);
  int i = blockIdx.x * blockDim.x + threadIdx.x;
  if (i >= K * N) return;
  int n = i / K, k = i - n * K;
  dst[i] = f2bf(loadExt(src, (long)k * N + n, f32));
}

// ---------------- rel-pos bias table: btab[head][n*50+m] (padded stride 50) --
__global__ void biastab_kernel(const bf16* __restrict__ rpb,  // canonical [169*6]
                               bf16* __restrict__ btab) {     // [6*2450]
  int i = blockIdx.x * blockDim.x + threadIdx.x;
  if (i >= 6 * 2450) return;
  int head = i / 2450, r = i - head * 2450;
  int n = r / 50, m = r - n * 50;
  float v = 0.f;
  if (n < 49 && m < 49) {
    int r1 = n / 7, c1 = n - 7 * r1, r2 = m / 7, c2 = m - 7 * r2;
    v = bf2f(rpb[((r1 - r2 + 6) * 13 + (c1 - c2 + 6)) * 6 + head]);
  }
  btab[i] = f2bf(v);
}

// ---------------- LayerNorm: one wave per 192-elem row; external input ------
__global__ __launch_bounds__(256) void ln_kernel(const int* __restrict__ flagp,
                                                 const void* __restrict__ x, long row0,
                                                 const bf16* __restrict__ g,
                                                 const bf16* __restrict__ b,
                                                 bf16* __restrict__ out) {
  const int f32 = (flagp[0] == 0);
  const int row = blockIdx.x * 4 + (threadIdx.x >> 6);
  const int lane = threadIdx.x & 63;
  const long gbase = (row0 + row) * 192;
  float v0 = loadExt(x, gbase + lane, f32);
  float v1 = loadExt(x, gbase + lane + 64, f32);
  float v2 = loadExt(x, gbase + lane + 128, f32);
  float s = v0 + v1 + v2;
  #pragma unroll
  for (int off = 32; off > 0; off >>= 1) s += __shfl_xor(s, off, 64);
  const float mu = s * (1.0f / 192.0f);
  float d0 = v0 - mu, d1 = v1 - mu, d2 = v2 - mu;
  float vv = d0 * d0 + d1 * d1 + d2 * d2;
  #pragma unroll
  for (int off = 32; off > 0; off >>= 1) vv += __shfl_xor(vv, off, 64);
  const float rstd = rsqrtf(vv * (1.0f / 192.0f) + 1e-5f);
  bf16* orow = out + (long)row * 192;
  orow[lane]       = f2bf(d0 * rstd * bf2f(g[lane])       + bf2f(b[lane]));
  orow[lane + 64]  = f2bf(d1 * rstd * bf2f(g[lane + 64])  + bf2f(b[lane + 64]));
  orow[lane + 128] = f2bf(d2 * rstd * bf2f(g[lane + 128]) + bf2f(b[lane + 128]));
}

// ---------------- bf16 MFMA GEMM: C = A[M,K]*BT[N,K]^T + bias, epilogue -----
// EPI: 0 = bias, 1 = bias+GELU(exact), 2 = bias+residual.
template <int EPI>
__global__ __launch_bounds__(256) void gemm_bt(const bf16* __restrict__ A,
                                               const bf16* __restrict__ BT,
                                               const bf16* __restrict__ bias,
                                               const int* __restrict__ flagp,
                                               const void* res, int res_ext,
                                               void* out, int out_ext, long ext_row0,
                                               int M, int N, int K) {
  constexpr int LDA = 40;  // 32 + 8 pad
  __shared__ __align__(16) bf16 As[128 * LDA];
  __shared__ __align__(16) bf16 Bs[64 * LDA];
  const int xf32 = (flagp[0] == 0);
  const int tid = threadIdx.x;
  const int wave = tid >> 6;
  const int lane = tid & 63;
  const int l16 = lane & 15;
  const int quad = lane >> 4;
  const long m0 = (long)blockIdx.x * 128;
  const int n0 = blockIdx.y * 64;

  floatx4 acc[2][4];
  #pragma unroll
  for (int i = 0; i < 2; i++)
    #pragma unroll
    for (int j = 0; j < 4; j++) acc[i][j] = (floatx4){0.f, 0.f, 0.f, 0.f};

  const int arow0 = tid >> 2;
  const int arow1 = arow0 + 64;
  const int acol = (tid & 3) * 8;

  for (int k0 = 0; k0 < K; k0 += 32) {
    *(float4*)&As[arow0 * LDA + acol] = *(const float4*)&A[(m0 + arow0) * K + k0 + acol];
    *(float4*)&As[arow1 * LDA + acol] = *(const float4*)&A[(m0 + arow1) * K + k0 + acol];
    *(float4*)&Bs[arow0 * LDA + acol] = *(const float4*)&BT[(long)(n0 + arow0) * K + k0 + acol];
    __syncthreads();

    bf16x8 af[2], bfr[4];
    #pragma unroll
    for (int ms = 0; ms < 2; ms++)
      af[ms] = *(const bf16x8*)&As[(wave * 32 + ms * 16 + l16) * LDA + quad * 8];
    #pragma unroll
    for (int ns = 0; ns < 4; ns++)
      bfr[ns] = *(const bf16x8*)&Bs[(ns * 16 + l16) * LDA + quad * 8];

    #pragma unroll
    for (int ms = 0; ms < 2; ms++)
      #pragma unroll
      for (int ns = 0; ns < 4; ns++)
        acc[ms][ns] = __builtin_amdgcn_mfma_f32_16x16x32_bf16(af[ms], bfr[ns], acc[ms][ns], 0, 0, 0);
    __syncthreads();
  }

  #pragma unroll
  for (int ms = 0; ms < 2; ms++) {
    #pragma unroll
    for (int ns = 0; ns < 4; ns++) {
      #pragma unroll
      for (int r = 0; r < 4; r++) {
        const long row = m0 + wave * 32 + ms * 16 + quad * 4 + r;
        const int col = n0 + ns * 16 + l16;
        float v = acc[ms][ns][r] + bf2f(bias[col]);
        if (EPI == 1) v = 0.5f * v * (1.0f + erff(v * 0.70710678118654752f));
        if (EPI == 2) v += loadExt(res, (ext_row0 + row) * N + col, res_ext && xf32);
        const long oi = out_ext ? (ext_row0 + row) * N + col : row * (long)N + col;
        storeExt(out, oi, out_ext && xf32, v);
      }
    }
  }
}

// ---------------- window attention v2: one wave per (window, head) ----------
// Lane n<49 owns query row n: scores s[49] + output o[32] in registers.
// K/V staged once to LDS as f32 (broadcast reads); bias from precomputed table.
__global__ __launch_bounds__(64) void attn_kernel(const bf16* __restrict__ qkv,  // [12544,576]
                                                  const bf16* __restrict__ btab, // [6,2450]
                                                  bf16* __restrict__ out) {      // [12544,192]
  __shared__ __align__(16) float ksh[49 * 32];
  __shared__ __align__(16) float vsh[49 * 32];
  __shared__ __align__(4) bf16 bsh[2450];
  __shared__ int rowIdx[49];
  __shared__ int regn[49];
  const int lane = threadIdx.x;
  const int unit = blockIdx.x;          // [0, 1536)
  const int head = unit % 6;
  const int wIdx = unit / 6;            // [0, 256)
  const int wh = wIdx >> 4;
  const int ww = wIdx & 15;

  if (lane < 49) {
    const int r = lane / 7, c = lane - 7 * (lane / 7);
    const int hr = wh * 7 + r;          // rolled-image coords
    const int wr = ww * 7 + c;
    int h = hr + 3; if (h >= 112) h -= 112;   // reverse the roll(-3) gather
    int w = wr + 3; if (w >= 112) w -= 112;
    rowIdx[lane] = h * 112 + w;               // batch-local row (original order)
    const int rh = hr < 105 ? 0 : (hr < 109 ? 1 : 2);
    const int rw = wr < 105 ? 0 : (wr < 109 ? 1 : 2);
    regn[lane] = rh * 3 + rw;
  }
  // bias stage (u32 copies; btab head-slice is 4-byte aligned: 2450*2B)
  {
    const unsigned int* bsrc = (const unsigned int*)(btab + head * 2450);
    unsigned int* bdst = (unsigned int*)bsh;
    for (int i = lane; i < 1225; i += 64) bdst[i] = bsrc[i];
  }
  __syncthreads();

  // K/V stage: 49 rows x 32 elems, converted to f32 once
  for (int i = lane; i < 196; i += 64) {
    const int r = i >> 2, c = (i & 3) * 8;
    const long base = (long)rowIdx[r] * 576 + head * 32 + c;
    bf16x8 kk = *(const bf16x8*)&qkv[base + 192];
    bf16x8 vv = *(const bf16x8*)&qkv[base + 384];
    #pragma unroll
    for (int j = 0; j < 8; j++) {
      ksh[r * 32 + c + j] = (float)kk[j];
      vsh[r * 32 + c + j] = (float)vv[j];
    }
  }
  __syncthreads();

  if (lane < 49) {
    const float scale = 0.17677669529663687f;  // 1/sqrt(32)
    // load my query row into registers (scaled)
    float qv[32];
    {
      const long qb = (long)rowIdx[lane] * 576 + head * 32;
      #pragma unroll
      for (int c = 0; c < 32; c += 8) {
        bf16x8 qq = *(const bf16x8*)&qkv[qb + c];
        #pragma unroll
        for (int j = 0; j < 8; j++) qv[c + j] = (float)qq[j] * scale;
      }
    }
    const int myreg = regn[lane];
    float s[49];
    #pragma unroll
    for (int m = 0; m < 49; m++) {
      float a = 0.f;
      #pragma unroll
      for (int d = 0; d < 32; d++) a += qv[d] * ksh[m * 32 + d];
      a += bf2f(bsh[lane * 50 + m]);
      if (regn[m] != myreg) a -= 100.0f;
      s[m] = a;
    }
    // softmax in registers
    float mx = s[0];
    #pragma unroll
    for (int m = 1; m < 49; m++) mx = fmaxf(mx, s[m]);
    float sum = 0.f;
    #pragma unroll
    for (int m = 0; m < 49; m++) { s[m] = __expf(s[m] - mx); sum += s[m]; }
    const float inv = 1.0f / sum;
    // PV
    float o[32];
    #pragma unroll
    for (int d = 0; d < 32; d++) o[d] = 0.f;
    #pragma unroll
    for (int m = 0; m < 49; m++) {
      const float p = s[m] * inv;
      #pragma unroll
      for (int d = 0; d < 32; d++) o[d] += p * vsh[m * 32 + d];
    }
    // store
    const long ob = (long)rowIdx[lane] * 192 + head * 32;
    #pragma unroll
    for (int c = 0; c < 32; c += 8) {
      bf16x8 ov;
      #pragma unroll
      for (int j = 0; j < 8; j++) ov[j] = (__bf16)o[c + j];
      *(bf16x8*)&out[ob + c] = ov;
    }
  }
}

// ---------------------------------------------------------------------------
// ws layout (bf16 elems after 16B flag header), total ~25.0 MB:
//   wsA [12544,192]=2,408,448  wsB [12544,768]=9,633,792
//   qkvT 110592  projT 36864  fc1T 147456  fc2T 147456
//   params 3510 (qkv_b,proj_b,n1g,n1b,n2g,n2b,fc1_b,fc2_b,rpb)  btab 14700
extern "C" void kernel_launch(void* const* d_in, const int* in_sizes, int n_in,
                              void* d_out, int out_size, void* d_ws, size_t ws_size,
                              hipStream_t stream) {
  const void* query   = d_in[0];
  const void* norm1_g = d_in[1];
  const void* norm1_b = d_in[2];
  const void* qkv_w   = d_in[3];
  const void* qkv_b   = d_in[4];
  const void* rpb     = d_in[5];
  const void* proj_w  = d_in[6];
  const void* proj_b  = d_in[7];
  const void* norm2_g = d_in[8];
  const void* norm2_b = d_in[9];
  const void* fc1_w   = d_in[10];
  const void* fc1_b   = d_in[11];
  const void* fc2_w   = d_in[12];
  const void* fc2_b   = d_in[13];

  const long MB_ = 12544;   // rows per batch image = rows per MLP chunk

  int* flag  = (int*)d_ws;
  bf16* base = (bf16*)((char*)d_ws + 16);
  bf16* wsA   = base;                   // 2,408,448
  bf16* wsB   = wsA + MB_ * 192;        // 9,633,792
  bf16* qkvT  = wsB + MB_ * 768;        // 110,592
  bf16* projT = qkvT + 110592;          // 36,864
  bf16* fc1T  = projT + 36864;          // 147,456
  bf16* fc2T  = fc1T + 147456;          // 147,456
  bf16* pPAR  = fc2T + 147456;          // 3,510
  bf16* pQKVB = pPAR;                   // 576
  bf16* pPRJB = pQKVB + 576;            // 192
  bf16* pN1G  = pPRJB + 192;            // 192
  bf16* pN1B  = pN1G + 192;             // 192
  bf16* pN2G  = pN1B + 192;             // 192
  bf16* pN2B  = pN2G + 192;             // 192
  bf16* pFC1B = pN2B + 192;             // 768
  bf16* pFC2B = pFC1B + 768;            // 192
  bf16* pRPB  = pFC2B + 192;            // 1,014
  bf16* btab  = pPAR + 3510;            // 14,700

  detect_kernel<<<1, 64, 0, stream>>>((const unsigned int*)query, flag);
  cvt_params_kernel<<<14, 256, 0, stream>>>(flag, qkv_b, proj_b, norm1_g, norm1_b,
                                            norm2_g, norm2_b, fc1_b, fc2_b, rpb, pPAR);
  cvtT_kernel<<<(192 * 576 + 255) / 256, 256, 0, stream>>>(flag, qkv_w, qkvT, 192, 576);
  cvtT_kernel<<<(192 * 192 + 255) / 256, 256, 0, stream>>>(flag, proj_w, projT, 192, 192);
  cvtT_kernel<<<(192 * 768 + 255) / 256, 256, 0, stream>>>(flag, fc1_w, fc1T, 192, 768);
  cvtT_kernel<<<(768 * 192 + 255) / 256, 256, 0, stream>>>(flag, fc2_w, fc2T, 768, 192);
  biastab_kernel<<<(6 * 2450 + 255) / 256, 256, 0, stream>>>(pRPB, btab);

  // ---- attention phase, per batch image ----
  for (int b = 0; b < 8; b++) {
    const long r0 = b * MB_;
    ln_kernel<<<MB_ / 4, 256, 0, stream>>>(flag, query, r0, pN1G, pN1B, wsA);
    gemm_bt<0><<<dim3(98, 9), 256, 0, stream>>>(wsA, qkvT, pQKVB, flag,
                                                nullptr, 0, wsB, 0, 0, (int)MB_, 576, 192);
    attn_kernel<<<1536, 64, 0, stream>>>(wsB, btab, wsA);
    gemm_bt<2><<<dim3(98, 3), 256, 0, stream>>>(wsA, projT, pPRJB, flag,
                                                query, 1, d_out, 1, r0, (int)MB_, 192, 192);
  }

  // ---- MLP phase, per 12544-row chunk ----
  for (int c = 0; c < 8; c++) {
    const long r0 = c * MB_;
    ln_kernel<<<MB_ / 4, 256, 0, stream>>>(flag, d_out, r0, pN2G, pN2B, wsA);
    gemm_bt<1><<<dim3(98, 12), 256, 0, stream>>>(wsA, fc1T, pFC1B, flag,
                                                 nullptr, 0, wsB, 0, 0, (int)MB_, 768, 192);
    gemm_bt<2><<<dim3(98, 3), 256, 0, stream>>>(wsB, fc2T, pFC2B, flag,
                                                d_out, 1, d_out, 1, r0, (int)MB_, 192, 768);
  }
}

// Round 6
// 851.407 us; speedup vs baseline: 2.0962x; 1.3517x over previous
//
#include <hip/hip_runtime.h>
#include <hip/hip_bf16.h>
#include <math.h>

using bf16 = __hip_bfloat16;
typedef __bf16 bf16x8 __attribute__((ext_vector_type(8)));
typedef float floatx4 __attribute__((ext_vector_type(4)));

__device__ __forceinline__ float bf2f(bf16 x) { return __bfloat162float(x); }
__device__ __forceinline__ bf16 f2bf(float x) { return __float2bfloat16(x); }

// flag semantics: flagp[0] == 1 -> external tensors are bf16; 0 -> float32.
__device__ __forceinline__ float loadExt(const void* p, long i, int f32) {
  return f32 ? ((const float*)p)[i] : bf2f(((const bf16*)p)[i]);
}
__device__ __forceinline__ void storeExt(void* p, long i, int f32, float v) {
  if (f32) ((float*)p)[i] = v;
  else     ((bf16*)p)[i] = f2bf(v);
}

// ---------------- dtype detector: 1 wave, inspects low 16 bits of 64 words ---
__global__ void detect_kernel(const unsigned int* __restrict__ q, int* __restrict__ flag) {
  const int lane = threadIdx.x;
  const unsigned int w = q[lane];
  const unsigned int lo = w & 0xffffu;
  const unsigned int e = (lo >> 7) & 0xffu;
  const bool ok = (lo == 0u) || (e >= 100u && e <= 141u);
  const unsigned long long m = __ballot(ok);
  if (lane == 0) flag[0] = (__popcll(m) == 64) ? 1 : 0;
}

// ---------------- combined 1-D param convert: 9 tensors -> contiguous bf16 ---
__global__ void cvt_params_kernel(const int* __restrict__ flagp,
                                  const void* qkv_b, const void* proj_b,
                                  const void* n1g, const void* n1b,
                                  const void* n2g, const void* n2b,
                                  const void* fc1_b, const void* fc2_b,
                                  const void* rpb, bf16* __restrict__ dst) {
  const int f32 = (flagp[0] == 0);
  int i = blockIdx.x * blockDim.x + threadIdx.x;
  if (i >= 3510) return;
  const void* src; int j = i;
  if      (j < 576)  { src = qkv_b; }
  else if ((j -= 576)  < 192) { src = proj_b; }
  else if ((j -= 192)  < 192) { src = n1g; }
  else if ((j -= 192)  < 192) { src = n1b; }
  else if ((j -= 192)  < 192) { src = n2g; }
  else if ((j -= 192)  < 192) { src = n2b; }
  else if ((j -= 192)  < 768) { src = fc1_b; }
  else if ((j -= 768)  < 192) { src = fc2_b; }
  else { j -= 192; src = rpb; }
  dst[i] = f2bf(loadExt(src, j, f32));
}

// ---------------- fused convert + transpose: src[K,N] (ext) -> dst[N,K] bf16 -
__global__ void cvtT_kernel(const int* __restrict__ flagp, const void* __restrict__ src,
                            bf16* __restrict__ dst, int K, int N) {
  const int f32 = (flagp[0] == 0);
  int i = blockIdx.x * blockDim.x + threadIdx.x;
  if (i >= K * N) return;
  int n = i / K, k = i - n * K;
  dst[i] = f2bf(loadExt(src, (long)k * N + n, f32));
}

// ---------------- rel-pos bias table: btab[head][n*50+m] (padded stride 50) --
__global__ void biastab_kernel(const bf16* __restrict__ rpb,
                               bf16* __restrict__ btab) {
  int i = blockIdx.x * blockDim.x + threadIdx.x;
  if (i >= 6 * 2450) return;
  int head = i / 2450, r = i - head * 2450;
  int n = r / 50, m = r - n * 50;
  float v = 0.f;
  if (n < 49 && m < 49) {
    int r1 = n / 7, c1 = n - 7 * r1, r2 = m / 7, c2 = m - 7 * r2;
    v = bf2f(rpb[((r1 - r2 + 6) * 13 + (c1 - c2 + 6)) * 6 + head]);
  }
  btab[i] = f2bf(v);
}

// ---------------- LayerNorm: one wave per 192-elem row --------------------
// ext=1: x may be fp32/bf16 per flag; ext=0: x is internal bf16.
__global__ __launch_bounds__(256) void ln_kernel(const int* __restrict__ flagp, int ext,
                                                 const void* __restrict__ x,
                                                 const bf16* __restrict__ g,
                                                 const bf16* __restrict__ b,
                                                 bf16* __restrict__ out) {
  const int f32 = ext && (flagp[0] == 0);
  const long row = (long)blockIdx.x * 4 + (threadIdx.x >> 6);
  const int lane = threadIdx.x & 63;
  const long gbase = row * 192;
  float v0 = loadExt(x, gbase + lane, f32);
  float v1 = loadExt(x, gbase + lane + 64, f32);
  float v2 = loadExt(x, gbase + lane + 128, f32);
  float s = v0 + v1 + v2;
  #pragma unroll
  for (int off = 32; off > 0; off >>= 1) s += __shfl_xor(s, off, 64);
  const float mu = s * (1.0f / 192.0f);
  float d0 = v0 - mu, d1 = v1 - mu, d2 = v2 - mu;
  float vv = d0 * d0 + d1 * d1 + d2 * d2;
  #pragma unroll
  for (int off = 32; off > 0; off >>= 1) vv += __shfl_xor(vv, off, 64);
  const float rstd = rsqrtf(vv * (1.0f / 192.0f) + 1e-5f);
  bf16* orow = out + row * 192;
  orow[lane]       = f2bf(d0 * rstd * bf2f(g[lane])       + bf2f(b[lane]));
  orow[lane + 64]  = f2bf(d1 * rstd * bf2f(g[lane + 64])  + bf2f(b[lane + 64]));
  orow[lane + 128] = f2bf(d2 * rstd * bf2f(g[lane + 128]) + bf2f(b[lane + 128]));
}

// ---------------- bf16 MFMA GEMM: C = A[M,K]*BT[N,K]^T + bias, epilogue -----
// EPI: 0 = bias, 1 = bias+GELU(exact), 2 = bias+residual.
// res: res_ext=1 -> external dtype per flag, else bf16. out likewise.
template <int EPI>
__global__ __launch_bounds__(256) void gemm_bt(const bf16* __restrict__ A,
                                               const bf16* __restrict__ BT,
                                               const bf16* __restrict__ bias,
                                               const int* __restrict__ flagp,
                                               const void* res, int res_ext,
                                               void* out, int out_ext,
                                               int M, int N, int K) {
  constexpr int LDA = 40;  // 32 + 8 pad
  __shared__ __align__(16) bf16 As[128 * LDA];
  __shared__ __align__(16) bf16 Bs[64 * LDA];
  const int xf32 = (flagp[0] == 0);
  const int tid = threadIdx.x;
  const int wave = tid >> 6;
  const int lane = tid & 63;
  const int l16 = lane & 15;
  const int quad = lane >> 4;
  const long m0 = (long)blockIdx.x * 128;
  const int n0 = blockIdx.y * 64;

  floatx4 acc[2][4];
  #pragma unroll
  for (int i = 0; i < 2; i++)
    #pragma unroll
    for (int j = 0; j < 4; j++) acc[i][j] = (floatx4){0.f, 0.f, 0.f, 0.f};

  const int arow0 = tid >> 2;
  const int arow1 = arow0 + 64;
  const int acol = (tid & 3) * 8;

  for (int k0 = 0; k0 < K; k0 += 32) {
    *(float4*)&As[arow0 * LDA + acol] = *(const float4*)&A[(m0 + arow0) * K + k0 + acol];
    *(float4*)&As[arow1 * LDA + acol] = *(const float4*)&A[(m0 + arow1) * K + k0 + acol];
    *(float4*)&Bs[arow0 * LDA + acol] = *(const float4*)&BT[(long)(n0 + arow0) * K + k0 + acol];
    __syncthreads();

    bf16x8 af[2], bfr[4];
    #pragma unroll
    for (int ms = 0; ms < 2; ms++)
      af[ms] = *(const bf16x8*)&As[(wave * 32 + ms * 16 + l16) * LDA + quad * 8];
    #pragma unroll
    for (int ns = 0; ns < 4; ns++)
      bfr[ns] = *(const bf16x8*)&Bs[(ns * 16 + l16) * LDA + quad * 8];

    #pragma unroll
    for (int ms = 0; ms < 2; ms++)
      #pragma unroll
      for (int ns = 0; ns < 4; ns++)
        acc[ms][ns] = __builtin_amdgcn_mfma_f32_16x16x32_bf16(af[ms], bfr[ns], acc[ms][ns], 0, 0, 0);
    __syncthreads();
  }

  #pragma unroll
  for (int ms = 0; ms < 2; ms++) {
    #pragma unroll
    for (int ns = 0; ns < 4; ns++) {
      #pragma unroll
      for (int r = 0; r < 4; r++) {
        const long row = m0 + wave * 32 + ms * 16 + quad * 4 + r;
        const int col = n0 + ns * 16 + l16;
        float v = acc[ms][ns][r] + bf2f(bias[col]);
        if (EPI == 1) v = 0.5f * v * (1.0f + erff(v * 0.70710678118654752f));
        if (EPI == 2) v += loadExt(res, row * (long)N + col, res_ext && xf32);
        storeExt(out, row * (long)N + col, out_ext && xf32, v);
      }
    }
  }
}

// ---------------- window attention: one wave per (window, head), full batch -
__global__ __launch_bounds__(64) void attn_kernel(const bf16* __restrict__ qkv,  // [100352,576]
                                                  const bf16* __restrict__ btab, // [6,2450]
                                                  bf16* __restrict__ out) {      // [100352,192]
  __shared__ __align__(16) float ksh[49 * 32];
  __shared__ __align__(16) float vsh[49 * 32];
  __shared__ __align__(4) bf16 bsh[2450];
  __shared__ int rowIdx[49];
  __shared__ int regn[49];
  const int lane = threadIdx.x;
  const int unit = blockIdx.x;          // [0, 12288)
  const int head = unit % 6;
  const int wIdx = unit / 6;            // [0, 2048)
  const int b = wIdx >> 8;
  const int w2 = wIdx & 255;
  const int wh = w2 >> 4;
  const int ww = w2 & 15;

  if (lane < 49) {
    const int r = lane / 7, c = lane - 7 * (lane / 7);
    const int hr = wh * 7 + r;          // rolled-image coords
    const int wr = ww * 7 + c;
    int h = hr + 3; if (h >= 112) h -= 112;
    int w = wr + 3; if (w >= 112) w -= 112;
    rowIdx[lane] = b * 12544 + h * 112 + w;
    const int rh = hr < 105 ? 0 : (hr < 109 ? 1 : 2);
    const int rw = wr < 105 ? 0 : (wr < 109 ? 1 : 2);
    regn[lane] = rh * 3 + rw;
  }
  {
    const unsigned int* bsrc = (const unsigned int*)(btab + head * 2450);
    unsigned int* bdst = (unsigned int*)bsh;
    for (int i = lane; i < 1225; i += 64) bdst[i] = bsrc[i];
  }
  __syncthreads();

  for (int i = lane; i < 196; i += 64) {
    const int r = i >> 2, c = (i & 3) * 8;
    const long base = (long)rowIdx[r] * 576 + head * 32 + c;
    bf16x8 kk = *(const bf16x8*)&qkv[base + 192];
    bf16x8 vv = *(const bf16x8*)&qkv[base + 384];
    #pragma unroll
    for (int j = 0; j < 8; j++) {
      ksh[r * 32 + c + j] = (float)kk[j];
      vsh[r * 32 + c + j] = (float)vv[j];
    }
  }
  __syncthreads();

  if (lane < 49) {
    const float scale = 0.17677669529663687f;  // 1/sqrt(32)
    float qv[32];
    {
      const long qb = (long)rowIdx[lane] * 576 + head * 32;
      #pragma unroll
      for (int c = 0; c < 32; c += 8) {
        bf16x8 qq = *(const bf16x8*)&qkv[qb + c];
        #pragma unroll
        for (int j = 0; j < 8; j++) qv[c + j] = (float)qq[j] * scale;
      }
    }
    const int myreg = regn[lane];
    float s[49];
    #pragma unroll
    for (int m = 0; m < 49; m++) {
      float a = 0.f;
      #pragma unroll
      for (int d = 0; d < 32; d++) a += qv[d] * ksh[m * 32 + d];
      a += bf2f(bsh[lane * 50 + m]);
      if (regn[m] != myreg) a -= 100.0f;
      s[m] = a;
    }
    float mx = s[0];
    #pragma unroll
    for (int m = 1; m < 49; m++) mx = fmaxf(mx, s[m]);
    float sum = 0.f;
    #pragma unroll
    for (int m = 0; m < 49; m++) { s[m] = __expf(s[m] - mx); sum += s[m]; }
    const float inv = 1.0f / sum;
    float o[32];
    #pragma unroll
    for (int d = 0; d < 32; d++) o[d] = 0.f;
    #pragma unroll
    for (int m = 0; m < 49; m++) {
      const float p = s[m] * inv;
      #pragma unroll
      for (int d = 0; d < 32; d++) o[d] += p * vsh[m * 32 + d];
    }
    const long ob = (long)rowIdx[lane] * 192 + head * 32;
    #pragma unroll
    for (int c = 0; c < 32; c += 8) {
      bf16x8 ov;
      #pragma unroll
      for (int j = 0; j < 8; j++) ov[j] = (__bf16)o[c + j];
      *(bf16x8*)&out[ob + c] = ov;
    }
  }
}

// ---------------------------------------------------------------------------
// ws layout (bf16 after 16B flag header), total ~231.7 MB (ws_size ~308 MB):
//   wsA  [100352,192] = 19,267,584   (ln1 out / attn out / ln2 out)
//   wsB  [100352,768] = 77,070,336   (qkv [.,576] then fc1 hidden [.,768])
//   xbuf [100352,192] = 19,267,584   (attention-branch residual x, bf16)
//   qkvT 110592  projT 36864  fc1T 147456  fc2T 147456  params 3510  btab 14700
extern "C" void kernel_launch(void* const* d_in, const int* in_sizes, int n_in,
                              void* d_out, int out_size, void* d_ws, size_t ws_size,
                              hipStream_t stream) {
  const void* query   = d_in[0];
  const void* norm1_g = d_in[1];
  const void* norm1_b = d_in[2];
  const void* qkv_w   = d_in[3];
  const void* qkv_b   = d_in[4];
  const void* rpb     = d_in[5];
  const void* proj_w  = d_in[6];
  const void* proj_b  = d_in[7];
  const void* norm2_g = d_in[8];
  const void* norm2_b = d_in[9];
  const void* fc1_w   = d_in[10];
  const void* fc1_b   = d_in[11];
  const void* fc2_w   = d_in[12];
  const void* fc2_b   = d_in[13];

  const long M = 100352;

  int* flag  = (int*)d_ws;
  bf16* base = (bf16*)((char*)d_ws + 16);
  bf16* wsA   = base;                   // 19,267,584
  bf16* wsB   = wsA + M * 192;          // 77,070,336
  bf16* xbuf  = wsB + M * 768;          // 19,267,584
  bf16* qkvT  = xbuf + M * 192;         // 110,592
  bf16* projT = qkvT + 110592;          // 36,864
  bf16* fc1T  = projT + 36864;          // 147,456
  bf16* fc2T  = fc1T + 147456;          // 147,456
  bf16* pPAR  = fc2T + 147456;          // 3,510
  bf16* pQKVB = pPAR;                   // 576
  bf16* pPRJB = pQKVB + 576;            // 192
  bf16* pN1G  = pPRJB + 192;
  bf16* pN1B  = pN1G + 192;
  bf16* pN2G  = pN1B + 192;
  bf16* pN2B  = pN2G + 192;
  bf16* pFC1B = pN2B + 192;             // 768
  bf16* pFC2B = pFC1B + 768;            // 192
  bf16* pRPB  = pFC2B + 192;            // 1,014
  bf16* btab  = pPAR + 3510;            // 14,700

  detect_kernel<<<1, 64, 0, stream>>>((const unsigned int*)query, flag);
  cvt_params_kernel<<<14, 256, 0, stream>>>(flag, qkv_b, proj_b, norm1_g, norm1_b,
                                            norm2_g, norm2_b, fc1_b, fc2_b, rpb, pPAR);
  cvtT_kernel<<<(192 * 576 + 255) / 256, 256, 0, stream>>>(flag, qkv_w, qkvT, 192, 576);
  cvtT_kernel<<<(192 * 192 + 255) / 256, 256, 0, stream>>>(flag, proj_w, projT, 192, 192);
  cvtT_kernel<<<(192 * 768 + 255) / 256, 256, 0, stream>>>(flag, fc1_w, fc1T, 192, 768);
  cvtT_kernel<<<(768 * 192 + 255) / 256, 256, 0, stream>>>(flag, fc2_w, fc2T, 768, 192);
  biastab_kernel<<<(6 * 2450 + 255) / 256, 256, 0, stream>>>(pRPB, btab);

  // ---- attention branch (full M) ----
  ln_kernel<<<M / 4, 256, 0, stream>>>(flag, 1, query, pN1G, pN1B, wsA);
  gemm_bt<0><<<dim3(784, 9), 256, 0, stream>>>(wsA, qkvT, pQKVB, flag,
                                               nullptr, 0, wsB, 0, (int)M, 576, 192);
  attn_kernel<<<12288, 64, 0, stream>>>(wsB, btab, wsA);
  // x = query + attn @ proj_w + b -> xbuf (bf16 internal)
  gemm_bt<2><<<dim3(784, 3), 256, 0, stream>>>(wsA, projT, pPRJB, flag,
                                               query, 1, xbuf, 0, (int)M, 192, 192);

  // ---- MLP branch (full M) ----
  ln_kernel<<<M / 4, 256, 0, stream>>>(flag, 0, xbuf, pN2G, pN2B, wsA);
  gemm_bt<1><<<dim3(784, 12), 256, 0, stream>>>(wsA, fc1T, pFC1B, flag,
                                                nullptr, 0, wsB, 0, (int)M, 768, 192);
  // out = x + h @ fc2 + b -> d_out (external dtype), residual from xbuf (bf16)
  gemm_bt<2><<<dim3(784, 3), 256, 0, stream>>>(wsB, fc2T, pFC2B, flag,
                                               xbuf, 0, d_out, 1, (int)M, 192, 768);
}